// Round 3
// baseline (245.175 us; speedup 1.0000x reference)
//
#include <hip/hip_runtime.h>

// Affinity propagation (spatial), round 3: TILE=64, strip-of-4 vectorized.
// guidance: [16, 8, 512, 512] f32, blur_depth: [16, 1, 512, 512] f32
// out: [16, 1, 512, 512] f32
//
// Per block: 64x64 output tile, 1024 threads. Result field in LDS (72x72,
// double-buffered, padded). Gates/base in registers: each thread owns up to
// 2 "strips" of 4 consecutive-x points. All 4 iterations update a FIXED
// 70-row x 72-col region; garbage propagates inward 1px/iter from the ring
// and never reaches the margin-4 output region.

#define TILE 64
#define G    72              // buffer side (TILE + 8)
#define GG   (G * G)         // 5184
#define NT   1024
#define SW   18              // strips per row (72 / 4)
#define NROW 70              // updated rows: y in [1, 71)
#define NSTRIP (SW * NROW)   // 1260
#define NSLOT 2

__launch_bounds__(NT)
__global__ void affprop_kernel(const float* __restrict__ guidance,
                               const float* __restrict__ blur,
                               float* __restrict__ out) {
    __shared__ float sAbuf[GG + 8];
    __shared__ float sBbuf[GG + 8];
    float* sA = sAbuf + 4;   // sA[-4 .. GG+3] valid; 16B-aligned
    float* sB = sBbuf + 4;

    const int tid = threadIdx.x;
    const int bx0 = blockIdx.x * TILE;
    const int by0 = blockIdx.y * TILE;
    const int b   = blockIdx.z;

    const int plane = 512 * 512;
    const float* __restrict__ blurB = blur + (long)b * plane;
    const float* __restrict__ guidB = guidance + (long)b * 8 * plane;
    float* __restrict__ outB = out + (long)b * plane;

    // ---- Phase 1: result_0 (blur, zero-padded) into sA; zero sB ring rows
    //      and both guard pads so every future read is finite.
    for (int i = tid; i < GG; i += NT) {
        int y = i / G, x = i - y * G;
        int gy = by0 - 4 + y, gx = bx0 - 4 + x;
        float v = 0.f;
        if ((unsigned)gy < 512u && (unsigned)gx < 512u)
            v = blurB[gy * 512 + gx];
        sA[i] = v;
    }
    if (tid < G) { sB[tid] = 0.f; sB[(G - 1) * G + tid] = 0.f; }
    if (tid < 4) {
        sAbuf[tid] = 0.f; sAbuf[GG + 4 + tid] = 0.f;
        sBbuf[tid] = 0.f; sBbuf[GG + 4 + tid] = 0.f;
    }
    __syncthreads();

    // ---- Phase 2: per-thread gates/base into registers (strip of 4 pts).
    float ga[NSLOT][8][4];
    float gb[NSLOT][4];
    int   gaddr[NSLOT];

    const int di[8] = {1, 1, 1, 0, 0, -1, -1, -1};
    const int dj[8] = {1, 0, -1, 1, -1, 1, 0, -1};

    const bool interior = (by0 >= 5) && (by0 <= 443) && (bx0 >= 5) && (bx0 <= 443);

    #pragma unroll
    for (int p = 0; p < NSLOT; ++p) {
        int s = tid + p * NT;
        bool act = (p == 0) || (s < NSTRIP);
        if (act) {
            int row = s / SW;
            int c   = s - row * SW;
            int y   = row + 1;
            int x0  = c * 4;
            int ga_ = y * G + x0;
            gaddr[p] = ga_;

            int gy  = by0 - 4 + y;
            int gx0 = bx0 - 4 + x0;
            float raw[4];
            { float4 r4 = *(const float4*)&sA[ga_];
              raw[0] = r4.x; raw[1] = r4.y; raw[2] = r4.z; raw[3] = r4.w; }

            if (interior) {
                float aw[4] = {0.f, 0.f, 0.f, 0.f};
                #pragma unroll
                for (int k = 0; k < 8; ++k) {
                    const float* gk = guidB + k * plane;
                    int off = (gy + di[k]) * 512 + gx0 + dj[k];
                    #pragma unroll
                    for (int j = 0; j < 4; ++j) {
                        float v = gk[off + j];
                        ga[p][k][j] = v;
                        aw[j] += fabsf(v);
                    }
                }
                #pragma unroll
                for (int j = 0; j < 4; ++j) {
                    float r = (aw[j] > 0.f) ? __builtin_amdgcn_rcpf(aw[j]) : 0.f;
                    float gs = 0.f;
                    #pragma unroll
                    for (int k = 0; k < 8; ++k) {
                        float w = ga[p][k][j] * r;
                        ga[p][k][j] = w;
                        gs += w;
                    }
                    gb[p][j] = (1.0f - gs) * raw[j];
                }
            } else {
                #pragma unroll
                for (int j = 0; j < 4; ++j) {
                    int gx = gx0 + j;
                    bool vp = ((unsigned)gy < 512u) && ((unsigned)gx < 512u);
                    float aw = 0.f;
                    float g[8];
                    #pragma unroll
                    for (int k = 0; k < 8; ++k) {
                        int yy = gy + di[k], xx = gx + dj[k];
                        bool vn = vp && ((unsigned)yy < 512u) && ((unsigned)xx < 512u);
                        int cy = min(max(yy, 0), 511);
                        int cx = min(max(xx, 0), 511);
                        float v = guidB[k * plane + cy * 512 + cx];
                        v = vn ? v : 0.f;
                        g[k] = v;
                        aw += fabsf(v);
                    }
                    float r = (aw > 0.f) ? __builtin_amdgcn_rcpf(aw) : 0.f;
                    float gs = 0.f;
                    #pragma unroll
                    for (int k = 0; k < 8; ++k) {
                        float w = g[k] * r;
                        ga[p][k][j] = w;
                        gs += w;
                    }
                    gb[p][j] = (1.0f - gs) * raw[j];
                }
            }
        }
    }
    // No barrier needed before iter 1: it reads sA (phase-1, already synced).

    // ---- Phase 3: 4 propagation iterations on the fixed region.
    auto prop = [&](const float* __restrict__ src, float* __restrict__ dst) {
        #pragma unroll
        for (int p = 0; p < NSLOT; ++p) {
            if (p == 0 || tid < (NSTRIP - NT)) {
                const float* s = src + gaddr[p];
                float4 up4 = *(const float4*)(s - G);
                float4 md4 = *(const float4*)(s);
                float4 dn4 = *(const float4*)(s + G);
                float u[6] = { s[-G - 1], up4.x, up4.y, up4.z, up4.w, s[-G + 4] };
                float m[6] = { s[-1],     md4.x, md4.y, md4.z, md4.w, s[4]      };
                float d[6] = { s[G - 1],  dn4.x, dn4.y, dn4.z, dn4.w, s[G + 4]  };
                float o[4];
                #pragma unroll
                for (int j = 0; j < 4; ++j) {
                    float acc = gb[p][j];
                    acc += ga[p][0][j] * d[j + 2];   // (+1,+1)
                    acc += ga[p][1][j] * d[j + 1];   // (+1, 0)
                    acc += ga[p][2][j] * d[j];       // (+1,-1)
                    acc += ga[p][3][j] * m[j + 2];   // ( 0,+1)
                    acc += ga[p][4][j] * m[j];       // ( 0,-1)
                    acc += ga[p][5][j] * u[j + 2];   // (-1,+1)
                    acc += ga[p][6][j] * u[j + 1];   // (-1, 0)
                    acc += ga[p][7][j] * u[j];       // (-1,-1)
                    o[j] = acc;
                }
                float4 o4; o4.x = o[0]; o4.y = o[1]; o4.z = o[2]; o4.w = o[3];
                *(float4*)(dst + gaddr[p]) = o4;
            }
        }
    };

    prop(sA, sB); __syncthreads();
    prop(sB, sA); __syncthreads();
    prop(sA, sB); __syncthreads();
    prop(sB, sA); __syncthreads();
    // Final result in sA, region [4, 68)^2.

    // ---- Phase 4: write 64x64 tile as float4 (one per thread).
    {
        int i  = tid;                       // 0..1023
        int yy = (i >> 4) + 4;              // 16 float4 per row
        int xx = ((i & 15) << 2) + 4;
        float4 v = *(const float4*)&sA[yy * G + xx];
        *(float4*)&outB[(by0 - 4 + yy) * 512 + (bx0 - 4 + xx)] = v;
    }
}

extern "C" void kernel_launch(void* const* d_in, const int* in_sizes, int n_in,
                              void* d_out, int out_size, void* d_ws, size_t ws_size,
                              hipStream_t stream) {
    const float* guidance = (const float*)d_in[0];
    const float* blur     = (const float*)d_in[1];
    float* out            = (float*)d_out;
    (void)d_ws; (void)ws_size;

    dim3 grid(512 / TILE, 512 / TILE, 16);  // 8 x 8 x 16 = 1024 blocks
    affprop_kernel<<<grid, NT, 0, stream>>>(guidance, blur, out);
}

// Round 4
// 242.793 us; speedup vs baseline: 1.0098x; 1.0098x over previous
//
#include <hip/hip_runtime.h>

// Affinity propagation (spatial), round 4: round-3 TILE=64 structure with
// REGISTER HEADROOM (__launch_bounds__(1024, 2)) so the per-thread gate
// state (~74 floats) stays in VGPRs instead of spilling to scratch.
// guidance: [16, 8, 512, 512] f32, blur_depth: [16, 1, 512, 512] f32
// out: [16, 1, 512, 512] f32

#define TILE 64
#define G    72              // buffer side (TILE + 8)
#define GG   (G * G)         // 5184
#define NT   1024
#define SW   18              // strips per row (72 / 4)
#define NROW 70              // updated rows: y in [1, 71)
#define NSTRIP (SW * NROW)   // 1260
#define NSLOT 2

__launch_bounds__(NT, 2)
__global__ void affprop_kernel(const float* __restrict__ guidance,
                               const float* __restrict__ blur,
                               float* __restrict__ out) {
    __shared__ float sAbuf[GG + 8];
    __shared__ float sBbuf[GG + 8];
    float* sA = sAbuf + 4;   // sA[-4 .. GG+3] valid; 16B-aligned
    float* sB = sBbuf + 4;

    const int tid = threadIdx.x;
    const int bx0 = blockIdx.x * TILE;
    const int by0 = blockIdx.y * TILE;
    const int b   = blockIdx.z;

    const int plane = 512 * 512;
    const float* __restrict__ blurB = blur + (long)b * plane;
    const float* __restrict__ guidB = guidance + (long)b * 8 * plane;
    float* __restrict__ outB = out + (long)b * plane;

    const bool interior = (by0 >= 5) && (by0 <= 443) && (bx0 >= 5) && (bx0 <= 443);

    // ---- Phase 1: result_0 (blur, zero-padded) into sA; zero sB ring rows
    //      and both guard pads so every future read is finite.
    if (interior) {
        // whole 72x72 window in-bounds; float4 loads (both sides 16B-aligned)
        for (int c = tid; c < GG / 4; c += NT) {
            int y = c / SW, x = (c - y * SW) * 4;
            float4 v = *(const float4*)&blurB[(by0 - 4 + y) * 512 + (bx0 - 4 + x)];
            *(float4*)&sA[y * G + x] = v;
        }
    } else {
        for (int i = tid; i < GG; i += NT) {
            int y = i / G, x = i - y * G;
            int gy = by0 - 4 + y, gx = bx0 - 4 + x;
            float v = 0.f;
            if ((unsigned)gy < 512u && (unsigned)gx < 512u)
                v = blurB[gy * 512 + gx];
            sA[i] = v;
        }
    }
    if (tid < G) { sB[tid] = 0.f; sB[(G - 1) * G + tid] = 0.f; }
    if (tid < 4) {
        sAbuf[tid] = 0.f; sAbuf[GG + 4 + tid] = 0.f;
        sBbuf[tid] = 0.f; sBbuf[GG + 4 + tid] = 0.f;
    }
    __syncthreads();

    // ---- Phase 2: per-thread gates/base into registers (strips of 4 pts).
    float ga[NSLOT][8][4];
    float gb[NSLOT][4];
    int   gaddr[NSLOT];

    const int di[8] = {1, 1, 1, 0, 0, -1, -1, -1};
    const int dj[8] = {1, 0, -1, 1, -1, 1, 0, -1};

    #pragma unroll
    for (int p = 0; p < NSLOT; ++p) {
        int s = tid + p * NT;
        bool act = (p == 0) || (s < NSTRIP);
        if (act) {
            int row = s / SW;
            int c   = s - row * SW;
            int y   = row + 1;
            int x0  = c * 4;
            int ga_ = y * G + x0;
            gaddr[p] = ga_;

            int gy  = by0 - 4 + y;
            int gx0 = bx0 - 4 + x0;
            float raw[4];
            { float4 r4 = *(const float4*)&sA[ga_];
              raw[0] = r4.x; raw[1] = r4.y; raw[2] = r4.z; raw[3] = r4.w; }

            if (interior) {
                float aw[4] = {0.f, 0.f, 0.f, 0.f};
                #pragma unroll
                for (int k = 0; k < 8; ++k) {
                    const float* gk = guidB + k * plane;
                    int off = (gy + di[k]) * 512 + gx0 + dj[k];
                    #pragma unroll
                    for (int j = 0; j < 4; ++j) {
                        float v = gk[off + j];
                        ga[p][k][j] = v;
                        aw[j] += fabsf(v);
                    }
                }
                #pragma unroll
                for (int j = 0; j < 4; ++j) {
                    float r = (aw[j] > 0.f) ? __builtin_amdgcn_rcpf(aw[j]) : 0.f;
                    float gs = 0.f;
                    #pragma unroll
                    for (int k = 0; k < 8; ++k) {
                        float w = ga[p][k][j] * r;
                        ga[p][k][j] = w;
                        gs += w;
                    }
                    gb[p][j] = (1.0f - gs) * raw[j];
                }
            } else {
                #pragma unroll
                for (int j = 0; j < 4; ++j) {
                    int gx = gx0 + j;
                    bool vp = ((unsigned)gy < 512u) && ((unsigned)gx < 512u);
                    float aw = 0.f;
                    float g[8];
                    #pragma unroll
                    for (int k = 0; k < 8; ++k) {
                        int yy = gy + di[k], xx = gx + dj[k];
                        bool vn = vp && ((unsigned)yy < 512u) && ((unsigned)xx < 512u);
                        int cy = min(max(yy, 0), 511);
                        int cx = min(max(xx, 0), 511);
                        float v = guidB[k * plane + cy * 512 + cx];
                        v = vn ? v : 0.f;
                        g[k] = v;
                        aw += fabsf(v);
                    }
                    float r = (aw > 0.f) ? __builtin_amdgcn_rcpf(aw) : 0.f;
                    float gs = 0.f;
                    #pragma unroll
                    for (int k = 0; k < 8; ++k) {
                        float w = g[k] * r;
                        ga[p][k][j] = w;
                        gs += w;
                    }
                    gb[p][j] = (1.0f - gs) * raw[j];
                }
            }
        } else {
            // inactive slot: keep state defined (never stored thanks to the
            // same guard in the prop loop, but avoid uninitialized regs)
            #pragma unroll
            for (int k = 0; k < 8; ++k)
                #pragma unroll
                for (int j = 0; j < 4; ++j) ga[p][k][j] = 0.f;
            #pragma unroll
            for (int j = 0; j < 4; ++j) gb[p][j] = 0.f;
            gaddr[p] = 0;
        }
    }
    // No barrier needed before iter 1: it reads sA (phase-1, already synced).

    // ---- Phase 3: 4 propagation iterations on the fixed region.
    auto prop = [&](const float* __restrict__ src, float* __restrict__ dst) {
        #pragma unroll
        for (int p = 0; p < NSLOT; ++p) {
            if (p == 0 || tid < (NSTRIP - NT)) {
                const float* s = src + gaddr[p];
                float4 up4 = *(const float4*)(s - G);
                float4 md4 = *(const float4*)(s);
                float4 dn4 = *(const float4*)(s + G);
                float u[6] = { s[-G - 1], up4.x, up4.y, up4.z, up4.w, s[-G + 4] };
                float m[6] = { s[-1],     md4.x, md4.y, md4.z, md4.w, s[4]      };
                float d[6] = { s[G - 1],  dn4.x, dn4.y, dn4.z, dn4.w, s[G + 4]  };
                float o[4];
                #pragma unroll
                for (int j = 0; j < 4; ++j) {
                    float acc = gb[p][j];
                    acc += ga[p][0][j] * d[j + 2];   // (+1,+1)
                    acc += ga[p][1][j] * d[j + 1];   // (+1, 0)
                    acc += ga[p][2][j] * d[j];       // (+1,-1)
                    acc += ga[p][3][j] * m[j + 2];   // ( 0,+1)
                    acc += ga[p][4][j] * m[j];       // ( 0,-1)
                    acc += ga[p][5][j] * u[j + 2];   // (-1,+1)
                    acc += ga[p][6][j] * u[j + 1];   // (-1, 0)
                    acc += ga[p][7][j] * u[j];       // (-1,-1)
                    o[j] = acc;
                }
                float4 o4; o4.x = o[0]; o4.y = o[1]; o4.z = o[2]; o4.w = o[3];
                *(float4*)(dst + gaddr[p]) = o4;
            }
        }
    };

    prop(sA, sB); __syncthreads();
    prop(sB, sA); __syncthreads();
    prop(sA, sB); __syncthreads();
    prop(sB, sA); __syncthreads();
    // Final result in sA, region [4, 68)^2.

    // ---- Phase 4: write 64x64 tile as float4 (one per thread).
    {
        int i  = tid;                       // 0..1023
        int yy = (i >> 4) + 4;              // 16 float4 per row
        int xx = ((i & 15) << 2) + 4;
        float4 v = *(const float4*)&sA[yy * G + xx];
        *(float4*)&outB[(by0 - 4 + yy) * 512 + (bx0 - 4 + xx)] = v;
    }
}

extern "C" void kernel_launch(void* const* d_in, const int* in_sizes, int n_in,
                              void* d_out, int out_size, void* d_ws, size_t ws_size,
                              hipStream_t stream) {
    const float* guidance = (const float*)d_in[0];
    const float* blur     = (const float*)d_in[1];
    float* out            = (float*)d_out;
    (void)d_ws; (void)ws_size;

    dim3 grid(512 / TILE, 512 / TILE, 16);  // 8 x 8 x 16 = 1024 blocks
    affprop_kernel<<<grid, NT, 0, stream>>>(guidance, blur, out);
}

// Round 5
// 242.198 us; speedup vs baseline: 1.0123x; 1.0025x over previous
//
#include <hip/hip_runtime.h>

// Affinity propagation (spatial), round 5: round-4 structure, but force the
// register allocator to keep the per-thread gate state (~74 floats) in VGPRs:
// amdgpu_waves_per_eu(4,4) => budget exactly 4 waves/EU => 128 VGPR cap,
// 1 block/CU. Previous rounds spilled to scratch (VGPR=60 < live state).
// guidance: [16, 8, 512, 512] f32, blur_depth: [16, 1, 512, 512] f32
// out: [16, 1, 512, 512] f32

#define TILE 64
#define G    72              // buffer side (TILE + 8)
#define GG   (G * G)         // 5184
#define NT   1024
#define SW   18              // strips per row (72 / 4)
#define NROW 70              // updated rows: y in [1, 71)
#define NSTRIP (SW * NROW)   // 1260
#define NSLOT 2

__attribute__((amdgpu_waves_per_eu(4, 4)))
__launch_bounds__(NT)
__global__ void affprop_kernel(const float* __restrict__ guidance,
                               const float* __restrict__ blur,
                               float* __restrict__ out) {
    __shared__ float sAbuf[GG + 8];
    __shared__ float sBbuf[GG + 8];
    float* sA = sAbuf + 4;   // sA[-4 .. GG+3] valid; 16B-aligned
    float* sB = sBbuf + 4;

    const int tid = threadIdx.x;
    const int bx0 = blockIdx.x * TILE;
    const int by0 = blockIdx.y * TILE;
    const int b   = blockIdx.z;

    const int plane = 512 * 512;
    const float* __restrict__ blurB = blur + (long)b * plane;
    const float* __restrict__ guidB = guidance + (long)b * 8 * plane;
    float* __restrict__ outB = out + (long)b * plane;

    const bool interior = (by0 >= 5) && (by0 <= 443) && (bx0 >= 5) && (bx0 <= 443);

    // ---- Phase 1: result_0 (blur, zero-padded) into sA; zero sB ring rows
    //      and both guard pads so every future read is finite.
    if (interior) {
        for (int c = tid; c < GG / 4; c += NT) {
            int y = c / SW, x = (c - y * SW) * 4;
            float4 v = *(const float4*)&blurB[(by0 - 4 + y) * 512 + (bx0 - 4 + x)];
            *(float4*)&sA[y * G + x] = v;
        }
    } else {
        for (int i = tid; i < GG; i += NT) {
            int y = i / G, x = i - y * G;
            int gy = by0 - 4 + y, gx = bx0 - 4 + x;
            float v = 0.f;
            if ((unsigned)gy < 512u && (unsigned)gx < 512u)
                v = blurB[gy * 512 + gx];
            sA[i] = v;
        }
    }
    if (tid < G) { sB[tid] = 0.f; sB[(G - 1) * G + tid] = 0.f; }
    if (tid < 4) {
        sAbuf[tid] = 0.f; sAbuf[GG + 4 + tid] = 0.f;
        sBbuf[tid] = 0.f; sBbuf[GG + 4 + tid] = 0.f;
    }
    __syncthreads();

    // ---- Phase 2: per-thread gates/base into registers (strips of 4 pts).
    float ga[NSLOT][8][4];
    float gb[NSLOT][4];
    int   gaddr[NSLOT];

    const int di[8] = {1, 1, 1, 0, 0, -1, -1, -1};
    const int dj[8] = {1, 0, -1, 1, -1, 1, 0, -1};

    #pragma unroll
    for (int p = 0; p < NSLOT; ++p) {
        int s = tid + p * NT;
        bool act = (p == 0) || (s < NSTRIP);
        if (act) {
            int row = s / SW;
            int c   = s - row * SW;
            int y   = row + 1;
            int x0  = c * 4;
            int ga_ = y * G + x0;
            gaddr[p] = ga_;

            int gy  = by0 - 4 + y;
            int gx0 = bx0 - 4 + x0;
            float raw[4];
            { float4 r4 = *(const float4*)&sA[ga_];
              raw[0] = r4.x; raw[1] = r4.y; raw[2] = r4.z; raw[3] = r4.w; }

            if (interior) {
                float aw[4] = {0.f, 0.f, 0.f, 0.f};
                #pragma unroll
                for (int k = 0; k < 8; ++k) {
                    const float* gk = guidB + k * plane;
                    int off = (gy + di[k]) * 512 + gx0 + dj[k];
                    #pragma unroll
                    for (int j = 0; j < 4; ++j) {
                        float v = gk[off + j];
                        ga[p][k][j] = v;
                        aw[j] += fabsf(v);
                    }
                }
                #pragma unroll
                for (int j = 0; j < 4; ++j) {
                    float r = (aw[j] > 0.f) ? __builtin_amdgcn_rcpf(aw[j]) : 0.f;
                    float gs = 0.f;
                    #pragma unroll
                    for (int k = 0; k < 8; ++k) {
                        float w = ga[p][k][j] * r;
                        ga[p][k][j] = w;
                        gs += w;
                    }
                    gb[p][j] = (1.0f - gs) * raw[j];
                }
            } else {
                #pragma unroll
                for (int j = 0; j < 4; ++j) {
                    int gx = gx0 + j;
                    bool vp = ((unsigned)gy < 512u) && ((unsigned)gx < 512u);
                    float aw = 0.f;
                    float g[8];
                    #pragma unroll
                    for (int k = 0; k < 8; ++k) {
                        int yy = gy + di[k], xx = gx + dj[k];
                        bool vn = vp && ((unsigned)yy < 512u) && ((unsigned)xx < 512u);
                        int cy = min(max(yy, 0), 511);
                        int cx = min(max(xx, 0), 511);
                        float v = guidB[k * plane + cy * 512 + cx];
                        v = vn ? v : 0.f;
                        g[k] = v;
                        aw += fabsf(v);
                    }
                    float r = (aw > 0.f) ? __builtin_amdgcn_rcpf(aw) : 0.f;
                    float gs = 0.f;
                    #pragma unroll
                    for (int k = 0; k < 8; ++k) {
                        float w = g[k] * r;
                        ga[p][k][j] = w;
                        gs += w;
                    }
                    gb[p][j] = (1.0f - gs) * raw[j];
                }
            }
        } else {
            #pragma unroll
            for (int k = 0; k < 8; ++k)
                #pragma unroll
                for (int j = 0; j < 4; ++j) ga[p][k][j] = 0.f;
            #pragma unroll
            for (int j = 0; j < 4; ++j) gb[p][j] = 0.f;
            gaddr[p] = 0;
        }
    }
    // No barrier needed before iter 1: it reads sA (phase-1, already synced).

    // ---- Phase 3: 4 propagation iterations on the fixed region.
    auto prop = [&](const float* __restrict__ src, float* __restrict__ dst) {
        #pragma unroll
        for (int p = 0; p < NSLOT; ++p) {
            if (p == 0 || tid < (NSTRIP - NT)) {
                const float* s = src + gaddr[p];
                float4 up4 = *(const float4*)(s - G);
                float4 md4 = *(const float4*)(s);
                float4 dn4 = *(const float4*)(s + G);
                float u[6] = { s[-G - 1], up4.x, up4.y, up4.z, up4.w, s[-G + 4] };
                float m[6] = { s[-1],     md4.x, md4.y, md4.z, md4.w, s[4]      };
                float d[6] = { s[G - 1],  dn4.x, dn4.y, dn4.z, dn4.w, s[G + 4]  };
                float o[4];
                #pragma unroll
                for (int j = 0; j < 4; ++j) {
                    float acc = gb[p][j];
                    acc += ga[p][0][j] * d[j + 2];   // (+1,+1)
                    acc += ga[p][1][j] * d[j + 1];   // (+1, 0)
                    acc += ga[p][2][j] * d[j];       // (+1,-1)
                    acc += ga[p][3][j] * m[j + 2];   // ( 0,+1)
                    acc += ga[p][4][j] * m[j];       // ( 0,-1)
                    acc += ga[p][5][j] * u[j + 2];   // (-1,+1)
                    acc += ga[p][6][j] * u[j + 1];   // (-1, 0)
                    acc += ga[p][7][j] * u[j];       // (-1,-1)
                    o[j] = acc;
                }
                float4 o4; o4.x = o[0]; o4.y = o[1]; o4.z = o[2]; o4.w = o[3];
                *(float4*)(dst + gaddr[p]) = o4;
            }
        }
    };

    prop(sA, sB); __syncthreads();
    prop(sB, sA); __syncthreads();
    prop(sA, sB); __syncthreads();
    prop(sB, sA); __syncthreads();
    // Final result in sA, region [4, 68)^2.

    // ---- Phase 4: write 64x64 tile as float4 (one per thread).
    {
        int i  = tid;                       // 0..1023
        int yy = (i >> 4) + 4;              // 16 float4 per row
        int xx = ((i & 15) << 2) + 4;
        float4 v = *(const float4*)&sA[yy * G + xx];
        *(float4*)&outB[(by0 - 4 + yy) * 512 + (bx0 - 4 + xx)] = v;
    }
}

extern "C" void kernel_launch(void* const* d_in, const int* in_sizes, int n_in,
                              void* d_out, int out_size, void* d_ws, size_t ws_size,
                              hipStream_t stream) {
    const float* guidance = (const float*)d_in[0];
    const float* blur     = (const float*)d_in[1];
    float* out            = (float*)d_out;
    (void)d_ws; (void)ws_size;

    dim3 grid(512 / TILE, 512 / TILE, 16);  // 8 x 8 x 16 = 1024 blocks
    affprop_kernel<<<grid, NT, 0, stream>>>(guidance, blur, out);
}